// Round 5
// baseline (1393.407 us; speedup 1.0000x reference)
//
#include <hip/hip_runtime.h>
#include <stdint.h>

typedef __attribute__((ext_vector_type(8))) short short8;
typedef __attribute__((ext_vector_type(4))) float floatx4;

__device__ __forceinline__ float bf2f(unsigned short h) {
  union { unsigned int u; float f; } v; v.u = ((unsigned int)h) << 16; return v.f;
}
__device__ __forceinline__ unsigned short f2bf(float f) {
  union { float f; unsigned int u; } v; v.f = f;
  unsigned int r = v.u + 0x7fffu + ((v.u >> 16) & 1u);
  return (unsigned short)(r >> 16);
}

__device__ __forceinline__ void gll16(const void* g, void* l) {
  __builtin_amdgcn_global_load_lds((const __attribute__((address_space(1))) unsigned int*)g,
                                   (__attribute__((address_space(3))) unsigned int*)l, 16, 0, 0);
}

// DPP row_ror:K (rotation within each 16-lane row) — VALU pipe, builtin only (VOPC+DPP illegal).
template <int K>
__device__ __forceinline__ float rorf(float x) {
  return __int_as_float(__builtin_amdgcn_update_dpp(0, __float_as_int(x), 0x120 + K, 0xF, 0xF, false));
}
__device__ __forceinline__ float grpmax16(float v) {
  v = fmaxf(v, rorf<1>(v)); v = fmaxf(v, rorf<2>(v));
  v = fmaxf(v, rorf<4>(v)); v = fmaxf(v, rorf<8>(v));
  return v;
}
__device__ __forceinline__ float grpsum16(float v) {
  v += rorf<1>(v); v += rorf<2>(v); v += rorf<4>(v); v += rorf<8>(v);
  return v;
}
// ds_swizzle xor-16 (BitMode: xor<<10 | and 0x1F) — per 32-lane half, xor16 stays in-half.
__device__ __forceinline__ float swz16(float x) {
  return __int_as_float(__builtin_amdgcn_ds_swizzle(__float_as_int(x), 0x401F));
}
// count of {base's 16-group elements} > own; independent accumulator per call (breaks dep chain)
__device__ __forceinline__ int rank16(float base, float own, bool self) {
  int r = self ? 0 : (int)(base > own);
  r += (int)(rorf<1>(base) > own);  r += (int)(rorf<2>(base) > own);
  r += (int)(rorf<3>(base) > own);  r += (int)(rorf<4>(base) > own);
  r += (int)(rorf<5>(base) > own);  r += (int)(rorf<6>(base) > own);
  r += (int)(rorf<7>(base) > own);  r += (int)(rorf<8>(base) > own);
  r += (int)(rorf<9>(base) > own);  r += (int)(rorf<10>(base) > own);
  r += (int)(rorf<11>(base) > own); r += (int)(rorf<12>(base) > own);
  r += (int)(rorf<13>(base) > own); r += (int)(rorf<14>(base) > own);
  r += (int)(rorf<15>(base) > own);
  return r;
}

// ------------- weight transpose+convert: in f32 (K,N) -> out bf16 (N,K) -------------
__global__ __launch_bounds__(256) void transpose_kern(const float* __restrict__ in,
                                                      unsigned short* __restrict__ out,
                                                      int K, int N) {
  __shared__ float tile[32][33];
  const int tx = threadIdx.x & 31, ty = threadIdx.x >> 5;
  const int n0 = blockIdx.x * 32, k0 = blockIdx.y * 32;
#pragma unroll
  for (int i = 0; i < 4; ++i)
    tile[ty + 8 * i][tx] = in[(size_t)(k0 + ty + 8 * i) * N + n0 + tx];
  __syncthreads();
#pragma unroll
  for (int i = 0; i < 4; ++i)
    out[(size_t)(n0 + ty + 8 * i) * K + k0 + tx] = f2bf(tile[tx][ty + 8 * i]);
}

// ------------- LayerNorm f32 -> bf16 (+ optional roll/window-partition scatter) -------------
__global__ __launch_bounds__(256) void ln_kern(const float* __restrict__ x,
                                               const float* __restrict__ g,
                                               const float* __restrict__ b,
                                               unsigned short* __restrict__ out,
                                               int tokenBase, int scatter) {
  const int t = tokenBase + blockIdx.x;
  const float* xr = x + (size_t)t * 512;
  const int c = threadIdx.x * 2;
  const float x0 = xr[c], x1 = xr[c + 1];
  float s = x0 + x1, s2 = x0 * x0 + x1 * x1;
#pragma unroll
  for (int off = 32; off; off >>= 1) {
    s += __shfl_xor(s, off, 64);
    s2 += __shfl_xor(s2, off, 64);
  }
  __shared__ float red[2][4];
  const int l = threadIdx.x & 63, wv = threadIdx.x >> 6;
  if (l == 0) { red[0][wv] = s; red[1][wv] = s2; }
  __syncthreads();
  s = red[0][0] + red[0][1] + red[0][2] + red[0][3];
  s2 = red[1][0] + red[1][1] + red[1][2] + red[1][3];
  const float mean = s * (1.0f / 512.0f);
  const float var = s2 * (1.0f / 512.0f) - mean * mean;
  const float rstd = rsqrtf(var + 1e-5f);
  const float y0 = (x0 - mean) * rstd * g[c] + b[c];
  const float y1 = (x1 - mean) * rstd * g[c + 1] + b[c + 1];
  int orow;
  if (scatter) {
    const int bb = t >> 12, rem = t & 4095, h = rem >> 6, w = rem & 63;
    const int hp = (h + 60) & 63, wp = (w + 60) & 63;
    const int wh = hp >> 3, i = hp & 7, ww = wp >> 3, j = wp & 7;
    const int rg = ((bb << 6) + (wh << 3) + ww) * 64 + (i << 3) + j;
    orow = rg - tokenBase;
  } else {
    orow = blockIdx.x;
  }
  const unsigned int o = (unsigned int)f2bf(y0) | ((unsigned int)f2bf(y1) << 16);
  *(unsigned int*)(out + (size_t)orow * 512 + c) = o;
}

// ------------- GEMM: C = A(MxK,bf16) * Bt(NxK,bf16)^T + bias(f32), fused epilogues -------------
template <int EPI>
__global__ __launch_bounds__(256) void gemm_bt(const unsigned short* __restrict__ A,
                                               const unsigned short* __restrict__ Bt,
                                               const float* __restrict__ bias,
                                               void* __restrict__ outv,
                                               const float* __restrict__ res,
                                               int M, int N, int K, int rowBase) {
  __shared__ unsigned short As[128][32];
  __shared__ unsigned short Bs[128][32];
  const int tid = threadIdx.x;
  const int l = tid & 63, wv = tid >> 6;
  const int wm = wv >> 1, wn = wv & 1;
  const int bm = blockIdx.y * 128, bn = blockIdx.x * 128;

  floatx4 acc[4][4];
#pragma unroll
  for (int i = 0; i < 4; ++i)
#pragma unroll
    for (int j = 0; j < 4; ++j) acc[i][j] = {0.0f, 0.0f, 0.0f, 0.0f};

  const int srow = l >> 2;
  const int scol = (l & 3) * 8;

  for (int k0 = 0; k0 < K; k0 += 32) {
#pragma unroll
    for (int tt = 0; tt < 2; ++tt) {
      const int r = wv * 32 + tt * 16;
      gll16(A + (size_t)(bm + r + srow) * K + k0 + scol, &As[r][0]);
      gll16(Bt + (size_t)(bn + r + srow) * K + k0 + scol, &Bs[r][0]);
    }
    __syncthreads();
    short8 af[4], bfr[4];
#pragma unroll
    for (int mt = 0; mt < 4; ++mt)
      af[mt] = *(const short8*)&As[wm * 64 + mt * 16 + (l & 15)][(l >> 4) * 8];
#pragma unroll
    for (int nt = 0; nt < 4; ++nt)
      bfr[nt] = *(const short8*)&Bs[wn * 64 + nt * 16 + (l & 15)][(l >> 4) * 8];
#pragma unroll
    for (int mt = 0; mt < 4; ++mt)
#pragma unroll
      for (int nt = 0; nt < 4; ++nt)
        acc[mt][nt] = __builtin_amdgcn_mfma_f32_16x16x32_bf16(af[mt], bfr[nt], acc[mt][nt], 0, 0, 0);
    __syncthreads();
  }

#pragma unroll
  for (int mt = 0; mt < 4; ++mt) {
#pragma unroll
    for (int nt = 0; nt < 4; ++nt) {
      const int gcol = bn + wn * 64 + nt * 16 + (l & 15);
      const float bv = bias[gcol];
#pragma unroll
      for (int r = 0; r < 4; ++r) {
        const int grow = bm + wm * 64 + mt * 16 + (l >> 4) * 4 + r;
        float v = acc[mt][nt][r] + bv;
        if (EPI == 1) v = 0.5f * v * (1.0f + erff(v * 0.70710678118654752f));
        if (EPI == 2) {
          const int rg = rowBase + grow;
          const int bw = rg >> 6, n = rg & 63;
          const int bb = bw >> 6, wi = bw & 63;
          const int i = n >> 3, j = n & 7;
          const int hp = ((wi >> 3) << 3) + i;
          const int wp = ((wi & 7) << 3) + j;
          const int h = (hp + 4) & 63, w = (wp + 4) & 63;
          const size_t t = (size_t)((bb << 12) + (h << 6) + w);
          ((float*)outv)[t * 512 + gcol] = v + res[t * 512 + gcol];
        } else if (EPI == 3) {
          ((float*)outv)[(size_t)grow * 512 + gcol] = v + res[(size_t)grow * 512 + gcol];
        } else {
          ((unsigned short*)outv)[(size_t)grow * (size_t)N + gcol] = f2bf(v);
        }
      }
    }
  }
}

// ------------- attention per (window, head): QK^T + bias, top-48 softmax, P@V -------------
__global__ __launch_bounds__(256) void attn_kern(const unsigned short* __restrict__ qkv,
                                                 const float* __restrict__ relb,
                                                 unsigned short* __restrict__ attnout) {
  __shared__ float Ss[64][66];            // scores f32; row head reused for bf16 P after consumption
  __shared__ unsigned short VT[32][66];   // V transposed [d][key]
  __shared__ float biasL[240];

  const int u = blockIdx.x;
  const int bwl = u >> 4, head = u & 15;
  const int tid = threadIdx.x;
  const int l = tid & 63, wv = tid >> 6;

  {
    const int row = tid >> 2, d0 = (tid & 3) * 8;
    short8 v8 = *(const short8*)(qkv + (size_t)(bwl * 64 + row) * 1536 + 1024 + head * 32 + d0);
#pragma unroll
    for (int j = 0; j < 8; ++j) VT[d0 + j][row] = (unsigned short)v8[j];
  }
  if (tid < 225) biasL[tid] = relb[tid * 16 + head];
  __syncthreads();   // VT/biasL visible to all waves

  // S = scale*QK^T + rel_bias; bias idx strength-reduced: idx(n0+r, m0+16nt) = base + r - 30*nt
  {
    short8 a = *(const short8*)(qkv + (size_t)(bwl * 64 + wv * 16 + (l & 15)) * 1536 +
                                head * 32 + (l >> 4) * 8);
    const int n0 = wv * 16 + (l >> 4) * 4;
    const int m0 = l & 15;
    const int ibase = ((n0 >> 3) - (m0 >> 3) + 7) * 15 + ((n0 & 7) - (m0 & 7) + 7);
#pragma unroll
    for (int nt = 0; nt < 4; ++nt) {
      short8 bfr = *(const short8*)(qkv + (size_t)(bwl * 64 + nt * 16 + (l & 15)) * 1536 + 512 +
                                    head * 32 + (l >> 4) * 8);
      floatx4 z = {0.0f, 0.0f, 0.0f, 0.0f};
      floatx4 d = __builtin_amdgcn_mfma_f32_16x16x32_bf16(a, bfr, z, 0, 0, 0);
#pragma unroll
      for (int r = 0; r < 4; ++r)
        Ss[n0 + r][m0 + nt * 16] = fmaf(d[r], 0.17677669529663689f, biasL[ibase + r - 30 * nt]);
    }
  }

  // per-row top-48 + softmax; each wave consumes rows it wrote (no barrier).
  // rank = #{j: s_j > s_l}; select rank<48 (tie-keep superset, matches top_k value-set).
  float* srow_base = &Ss[wv * 16][0];
#pragma unroll 2
  for (int rr = 0; rr < 16; ++rr) {
    const float own = srow_base[rr * 66 + l];
    const float g1 = swz16(own);                 // lane^16
    const float g2 = __shfl_xor(own, 32, 64);    // lane^32
    const float g3 = swz16(g2);                  // lane^48
    const int r0 = rank16(own, own, true);       // 4 independent chains
    const int r1 = rank16(g1, own, false);
    const int r2 = rank16(g2, own, false);
    const int r3 = rank16(g3, own, false);
    const int rank = (r0 + r1) + (r2 + r3);
    const float mx = grpmax16(fmaxf(fmaxf(own, g1), fmaxf(g2, g3)));
    const float e = (rank < 48) ? __expf(own - mx) : 0.0f;
    float zs = grpsum16(e);
    zs += swz16(zs);
    zs += __shfl_xor(zs, 32, 64);
    ((unsigned short*)(srow_base + rr * 66))[l] = f2bf(e * __builtin_amdgcn_rcpf(zs));
  }

  // out = P (64x64) @ V (64x32); P rows are wave-private
  {
    floatx4 acc[2];
    acc[0] = {0.0f, 0.0f, 0.0f, 0.0f};
    acc[1] = {0.0f, 0.0f, 0.0f, 0.0f};
#pragma unroll
    for (int kh = 0; kh < 2; ++kh) {
      short8 pa = *(const short8*)((const unsigned short*)&Ss[wv * 16 + (l & 15)][0] +
                                   kh * 32 + (l >> 4) * 8);
#pragma unroll
      for (int nt = 0; nt < 2; ++nt) {
        short8 vb = *(const short8*)&VT[nt * 16 + (l & 15)][kh * 32 + (l >> 4) * 8];
        acc[nt] = __builtin_amdgcn_mfma_f32_16x16x32_bf16(pa, vb, acc[nt], 0, 0, 0);
      }
    }
#pragma unroll
    for (int nt = 0; nt < 2; ++nt)
#pragma unroll
      for (int r = 0; r < 4; ++r) {
        const int n = wv * 16 + (l >> 4) * 4 + r;
        const int dcol = nt * 16 + (l & 15);
        attnout[(size_t)(bwl * 64 + n) * 512 + head * 32 + dcol] = f2bf(acc[nt][r]);
      }
  }
}

// ---------------- launcher ----------------
extern "C" void kernel_launch(void* const* d_in, const int* in_sizes, int n_in,
                              void* d_out, int out_size, void* d_ws, size_t ws_size,
                              hipStream_t stream) {
  (void)in_sizes; (void)n_in; (void)out_size;
  const float* x      = (const float*)d_in[0];
  const float* n1g    = (const float*)d_in[1];
  const float* n1b    = (const float*)d_in[2];
  const float* qkv_w  = (const float*)d_in[3];
  const float* qkv_b  = (const float*)d_in[4];
  const float* relb   = (const float*)d_in[5];
  const float* proj_w = (const float*)d_in[6];
  const float* proj_b = (const float*)d_in[7];
  const float* n2g    = (const float*)d_in[8];
  const float* n2b    = (const float*)d_in[9];
  const float* fc1_w  = (const float*)d_in[10];
  const float* fc1_b  = (const float*)d_in[11];
  const float* fc2_w  = (const float*)d_in[12];
  const float* fc2_b  = (const float*)d_in[13];
  float* x2 = (float*)d_out;   // post-attention residual state lives in d_out (f32)

  unsigned short* qkvT  = (unsigned short*)d_ws;
  unsigned short* projT = qkvT + 1536 * 512;
  unsigned short* fc1T  = projT + 512 * 512;
  unsigned short* fc2T  = fc1T + 2048 * 512;
  const size_t wbytes = (size_t)(1536 * 512 + 512 * 512 + 2048 * 512 + 512 * 2048) * 2;
  size_t rem = ws_size > wbytes ? ws_size - wbytes : 0;
  int R = (int)(rem / 5120);
  R = (R / 4096) * 4096;
  if (R > 16384) R = 16384;
  if (R < 4096) R = 4096;
  const int nch = 65536 / R;
  unsigned short* bufA = (unsigned short*)((char*)d_ws + wbytes);
  unsigned short* bufB = bufA + (size_t)R * 512;

  transpose_kern<<<dim3(1536 / 32, 512 / 32), 256, 0, stream>>>(qkv_w, qkvT, 512, 1536);
  transpose_kern<<<dim3(512 / 32, 512 / 32), 256, 0, stream>>>(proj_w, projT, 512, 512);
  transpose_kern<<<dim3(2048 / 32, 512 / 32), 256, 0, stream>>>(fc1_w, fc1T, 512, 2048);
  transpose_kern<<<dim3(512 / 32, 2048 / 32), 256, 0, stream>>>(fc2_w, fc2T, 2048, 512);

  // merged per-chunk pipeline: keeps the chunk's x2 (16 MiB f32) L3-resident
  for (int cb = 0; cb < nch; ++cb) {
    ln_kern<<<R, 256, 0, stream>>>(x, n1g, n1b, bufA, cb * R, 1);
    gemm_bt<0><<<dim3(12, R / 128), 256, 0, stream>>>(bufA, qkvT, qkv_b, bufB, nullptr,
                                                      R, 1536, 512, 0);
    attn_kern<<<(R / 64) * 16, 256, 0, stream>>>(bufB, relb, bufA);
    gemm_bt<2><<<dim3(4, R / 128), 256, 0, stream>>>(bufA, projT, proj_b, x2, x,
                                                     R, 512, 512, cb * R);
    ln_kern<<<R, 256, 0, stream>>>(x2, n2g, n2b, bufA, cb * R, 0);
    gemm_bt<1><<<dim3(16, R / 128), 256, 0, stream>>>(bufA, fc1T, fc1_b, bufB, nullptr,
                                                      R, 2048, 512, 0);
    gemm_bt<3><<<dim3(4, R / 128), 256, 0, stream>>>(bufB, fc2T, fc2_b,
                                                     x2 + (size_t)cb * R * 512,
                                                     x2 + (size_t)cb * R * 512,
                                                     R, 512, 2048, 0);
  }
}

// Round 6
// 1207.348 us; speedup vs baseline: 1.1541x; 1.1541x over previous
//
#include <hip/hip_runtime.h>
#include <stdint.h>

typedef __attribute__((ext_vector_type(8))) short short8;
typedef __attribute__((ext_vector_type(4))) float floatx4;

__device__ __forceinline__ float bf2f(unsigned short h) {
  union { unsigned int u; float f; } v; v.u = ((unsigned int)h) << 16; return v.f;
}
__device__ __forceinline__ unsigned short f2bf(float f) {
  union { float f; unsigned int u; } v; v.f = f;
  unsigned int r = v.u + 0x7fffu + ((v.u >> 16) & 1u);
  return (unsigned short)(r >> 16);
}

__device__ __forceinline__ void gll16(const void* g, void* l) {
  __builtin_amdgcn_global_load_lds((const __attribute__((address_space(1))) unsigned int*)g,
                                   (__attribute__((address_space(3))) unsigned int*)l, 16, 0, 0);
}

// DPP row_ror:K (rotation within each 16-lane row) — VALU pipe.
template <int K>
__device__ __forceinline__ float rorf(float x) {
  return __int_as_float(__builtin_amdgcn_update_dpp(0, __float_as_int(x), 0x120 + K, 0xF, 0xF, false));
}
__device__ __forceinline__ float grpsum16(float v) {
  v += rorf<1>(v); v += rorf<2>(v); v += rorf<4>(v); v += rorf<8>(v);
  return v;
}
// ds_swizzle xor-16 (BitMode: xor<<10 | and 0x1F)
__device__ __forceinline__ float swz16(float x) {
  return __int_as_float(__builtin_amdgcn_ds_swizzle(__float_as_int(x), 0x401F));
}

// ------------- weight transpose+convert: in f32 (K,N) -> out bf16 (N,K) -------------
__global__ __launch_bounds__(256) void transpose_kern(const float* __restrict__ in,
                                                      unsigned short* __restrict__ out,
                                                      int K, int N) {
  __shared__ float tile[32][33];
  const int tx = threadIdx.x & 31, ty = threadIdx.x >> 5;
  const int n0 = blockIdx.x * 32, k0 = blockIdx.y * 32;
#pragma unroll
  for (int i = 0; i < 4; ++i)
    tile[ty + 8 * i][tx] = in[(size_t)(k0 + ty + 8 * i) * N + n0 + tx];
  __syncthreads();
#pragma unroll
  for (int i = 0; i < 4; ++i)
    out[(size_t)(n0 + ty + 8 * i) * K + k0 + tx] = f2bf(tile[tx][ty + 8 * i]);
}

// ------------- LayerNorm f32 -> bf16 (+ optional roll/window-partition scatter) -------------
__global__ __launch_bounds__(256) void ln_kern(const float* __restrict__ x,
                                               const float* __restrict__ g,
                                               const float* __restrict__ b,
                                               unsigned short* __restrict__ out,
                                               int tokenBase, int scatter) {
  const int t = tokenBase + blockIdx.x;
  const float* xr = x + (size_t)t * 512;
  const int c = threadIdx.x * 2;
  const float x0 = xr[c], x1 = xr[c + 1];
  float s = x0 + x1, s2 = x0 * x0 + x1 * x1;
#pragma unroll
  for (int off = 32; off; off >>= 1) {
    s += __shfl_xor(s, off, 64);
    s2 += __shfl_xor(s2, off, 64);
  }
  __shared__ float red[2][4];
  const int l = threadIdx.x & 63, wv = threadIdx.x >> 6;
  if (l == 0) { red[0][wv] = s; red[1][wv] = s2; }
  __syncthreads();
  s = red[0][0] + red[0][1] + red[0][2] + red[0][3];
  s2 = red[1][0] + red[1][1] + red[1][2] + red[1][3];
  const float mean = s * (1.0f / 512.0f);
  const float var = s2 * (1.0f / 512.0f) - mean * mean;
  const float rstd = rsqrtf(var + 1e-5f);
  const float y0 = (x0 - mean) * rstd * g[c] + b[c];
  const float y1 = (x1 - mean) * rstd * g[c + 1] + b[c + 1];
  int orow;
  if (scatter) {
    const int bb = t >> 12, rem = t & 4095, h = rem >> 6, w = rem & 63;
    const int hp = (h + 60) & 63, wp = (w + 60) & 63;
    const int wh = hp >> 3, i = hp & 7, ww = wp >> 3, j = wp & 7;
    const int rg = ((bb << 6) + (wh << 3) + ww) * 64 + (i << 3) + j;
    orow = rg - tokenBase;
  } else {
    orow = blockIdx.x;
  }
  const unsigned int o = (unsigned int)f2bf(y0) | ((unsigned int)f2bf(y1) << 16);
  *(unsigned int*)(out + (size_t)orow * 512 + c) = o;
}

// ------------- GEMM: C = A(MxK,bf16) * Bt(NxK,bf16)^T + bias(f32), fused epilogues -------------
template <int EPI>
__global__ __launch_bounds__(256) void gemm_bt(const unsigned short* __restrict__ A,
                                               const unsigned short* __restrict__ Bt,
                                               const float* __restrict__ bias,
                                               void* __restrict__ outv,
                                               const float* __restrict__ res,
                                               int M, int N, int K, int rowBase) {
  __shared__ unsigned short As[128][32];
  __shared__ unsigned short Bs[128][32];
  const int tid = threadIdx.x;
  const int l = tid & 63, wv = tid >> 6;
  const int wm = wv >> 1, wn = wv & 1;
  const int bm = blockIdx.y * 128, bn = blockIdx.x * 128;

  floatx4 acc[4][4];
#pragma unroll
  for (int i = 0; i < 4; ++i)
#pragma unroll
    for (int j = 0; j < 4; ++j) acc[i][j] = {0.0f, 0.0f, 0.0f, 0.0f};

  const int srow = l >> 2;
  const int scol = (l & 3) * 8;

  for (int k0 = 0; k0 < K; k0 += 32) {
#pragma unroll
    for (int tt = 0; tt < 2; ++tt) {
      const int r = wv * 32 + tt * 16;
      gll16(A + (size_t)(bm + r + srow) * K + k0 + scol, &As[r][0]);
      gll16(Bt + (size_t)(bn + r + srow) * K + k0 + scol, &Bs[r][0]);
    }
    __syncthreads();
    short8 af[4], bfr[4];
#pragma unroll
    for (int mt = 0; mt < 4; ++mt)
      af[mt] = *(const short8*)&As[wm * 64 + mt * 16 + (l & 15)][(l >> 4) * 8];
#pragma unroll
    for (int nt = 0; nt < 4; ++nt)
      bfr[nt] = *(const short8*)&Bs[wn * 64 + nt * 16 + (l & 15)][(l >> 4) * 8];
#pragma unroll
    for (int mt = 0; mt < 4; ++mt)
#pragma unroll
      for (int nt = 0; nt < 4; ++nt)
        acc[mt][nt] = __builtin_amdgcn_mfma_f32_16x16x32_bf16(af[mt], bfr[nt], acc[mt][nt], 0, 0, 0);
    __syncthreads();
  }

#pragma unroll
  for (int mt = 0; mt < 4; ++mt) {
#pragma unroll
    for (int nt = 0; nt < 4; ++nt) {
      const int gcol = bn + wn * 64 + nt * 16 + (l & 15);
      const float bv = bias[gcol];
#pragma unroll
      for (int r = 0; r < 4; ++r) {
        const int grow = bm + wm * 64 + mt * 16 + (l >> 4) * 4 + r;
        float v = acc[mt][nt][r] + bv;
        if (EPI == 1) v = 0.5f * v * (1.0f + erff(v * 0.70710678118654752f));
        if (EPI == 2) {
          const int rg = rowBase + grow;
          const int bw = rg >> 6, n = rg & 63;
          const int bb = bw >> 6, wi = bw & 63;
          const int i = n >> 3, j = n & 7;
          const int hp = ((wi >> 3) << 3) + i;
          const int wp = ((wi & 7) << 3) + j;
          const int h = (hp + 4) & 63, w = (wp + 4) & 63;
          const size_t t = (size_t)((bb << 12) + (h << 6) + w);
          ((float*)outv)[t * 512 + gcol] = v + res[t * 512 + gcol];
        } else if (EPI == 3) {
          ((float*)outv)[(size_t)grow * 512 + gcol] = v + res[(size_t)grow * 512 + gcol];
        } else {
          ((unsigned short*)outv)[(size_t)grow * (size_t)N + gcol] = f2bf(v);
        }
      }
    }
  }
}

// ------------- attention per (window, head): QK^T + bias, top-48 via radix-select, P@V -------------
__global__ __launch_bounds__(256) void attn_kern(const unsigned short* __restrict__ qkv,
                                                 const float* __restrict__ relb,
                                                 unsigned short* __restrict__ attnout) {
  __shared__ float Ss[64][66];            // scores f32; row head reused for bf16 P after consumption
  __shared__ unsigned short VT[32][66];   // V transposed [d][key]
  __shared__ float biasL[240];

  const int u = blockIdx.x;
  const int bwl = u >> 4, head = u & 15;
  const int tid = threadIdx.x;
  const int l = tid & 63, wv = tid >> 6;

  {
    const int row = tid >> 2, d0 = (tid & 3) * 8;
    short8 v8 = *(const short8*)(qkv + (size_t)(bwl * 64 + row) * 1536 + 1024 + head * 32 + d0);
#pragma unroll
    for (int j = 0; j < 8; ++j) VT[d0 + j][row] = (unsigned short)v8[j];
  }
  if (tid < 225) biasL[tid] = relb[tid * 16 + head];
  __syncthreads();   // VT/biasL visible to all waves

  // S = scale*QK^T + rel_bias; bias idx strength-reduced: idx(n0+r, m0+16nt) = base + r - 30*nt
  {
    short8 a = *(const short8*)(qkv + (size_t)(bwl * 64 + wv * 16 + (l & 15)) * 1536 +
                                head * 32 + (l >> 4) * 8);
    const int n0 = wv * 16 + (l >> 4) * 4;
    const int m0 = l & 15;
    const int ibase = ((n0 >> 3) - (m0 >> 3) + 7) * 15 + ((n0 & 7) - (m0 & 7) + 7);
#pragma unroll
    for (int nt = 0; nt < 4; ++nt) {
      short8 bfr = *(const short8*)(qkv + (size_t)(bwl * 64 + nt * 16 + (l & 15)) * 1536 + 512 +
                                    head * 32 + (l >> 4) * 8);
      floatx4 z = {0.0f, 0.0f, 0.0f, 0.0f};
      floatx4 d = __builtin_amdgcn_mfma_f32_16x16x32_bf16(a, bfr, z, 0, 0, 0);
#pragma unroll
      for (int r = 0; r < 4; ++r)
        Ss[n0 + r][m0 + nt * 16] = fmaf(d[r], 0.17677669529663689f, biasL[ibase + r - 30 * nt]);
    }
  }

  // per-row top-48 + softmax; each wave consumes rows it wrote (no barrier).
  // Threshold via MSB-first radix bisection: VALU cost 1 v_cmp/bit; count/select on SALU pipe.
  // keep = mapped >= t (superset under exact ties — same semantics as passing rounds).
  float* srow_base = &Ss[wv * 16][0];
#pragma unroll 1
  for (int rr = 0; rr < 16; ++rr) {
    const float own = srow_base[rr * 66 + l];
    const unsigned int uo = __float_as_uint(own);
    const unsigned int mapped = uo ^ ((unsigned int)((int)uo >> 31) | 0x80000000u);
    unsigned int p = 0;
#pragma unroll 1
    for (int b = 31; b >= 0; --b) {
      const unsigned int cand = p | (1u << b);
      const int c = __popcll(__ballot(mapped >= cand));
      if (c >= 48) {
        p = cand;
        if (c == 48) break;   // exactly 48 kept — threshold found
      }
    }
    // unmap threshold to float; softmax referenced to threshold (kept scores >= t, spread small)
    const float tf = __uint_as_float((p & 0x80000000u) ? (p ^ 0x80000000u) : ~p);
    const float e = (mapped >= p) ? __expf(own - tf) : 0.0f;
    float zs = grpsum16(e);
    zs += swz16(zs);
    zs += __shfl_xor(zs, 32, 64);
    ((unsigned short*)(srow_base + rr * 66))[l] = f2bf(e * __builtin_amdgcn_rcpf(zs));
  }

  // out = P (64x64) @ V (64x32); P rows are wave-private
  {
    floatx4 acc[2];
    acc[0] = {0.0f, 0.0f, 0.0f, 0.0f};
    acc[1] = {0.0f, 0.0f, 0.0f, 0.0f};
#pragma unroll
    for (int kh = 0; kh < 2; ++kh) {
      short8 pa = *(const short8*)((const unsigned short*)&Ss[wv * 16 + (l & 15)][0] +
                                   kh * 32 + (l >> 4) * 8);
#pragma unroll
      for (int nt = 0; nt < 2; ++nt) {
        short8 vb = *(const short8*)&VT[nt * 16 + (l & 15)][kh * 32 + (l >> 4) * 8];
        acc[nt] = __builtin_amdgcn_mfma_f32_16x16x32_bf16(pa, vb, acc[nt], 0, 0, 0);
      }
    }
#pragma unroll
    for (int nt = 0; nt < 2; ++nt)
#pragma unroll
      for (int r = 0; r < 4; ++r) {
        const int n = wv * 16 + (l >> 4) * 4 + r;
        const int dcol = nt * 16 + (l & 15);
        attnout[(size_t)(bwl * 64 + n) * 512 + head * 32 + dcol] = f2bf(acc[nt][r]);
      }
  }
}

// ---------------- launcher ----------------
extern "C" void kernel_launch(void* const* d_in, const int* in_sizes, int n_in,
                              void* d_out, int out_size, void* d_ws, size_t ws_size,
                              hipStream_t stream) {
  (void)in_sizes; (void)n_in; (void)out_size;
  const float* x      = (const float*)d_in[0];
  const float* n1g    = (const float*)d_in[1];
  const float* n1b    = (const float*)d_in[2];
  const float* qkv_w  = (const float*)d_in[3];
  const float* qkv_b  = (const float*)d_in[4];
  const float* relb   = (const float*)d_in[5];
  const float* proj_w = (const float*)d_in[6];
  const float* proj_b = (const float*)d_in[7];
  const float* n2g    = (const float*)d_in[8];
  const float* n2b    = (const float*)d_in[9];
  const float* fc1_w  = (const float*)d_in[10];
  const float* fc1_b  = (const float*)d_in[11];
  const float* fc2_w  = (const float*)d_in[12];
  const float* fc2_b  = (const float*)d_in[13];
  float* x2 = (float*)d_out;   // post-attention residual state lives in d_out (f32)

  unsigned short* qkvT  = (unsigned short*)d_ws;
  unsigned short* projT = qkvT + 1536 * 512;
  unsigned short* fc1T  = projT + 512 * 512;
  unsigned short* fc2T  = fc1T + 2048 * 512;
  const size_t wbytes = (size_t)(1536 * 512 + 512 * 512 + 2048 * 512 + 512 * 2048) * 2;
  size_t rem = ws_size > wbytes ? ws_size - wbytes : 0;
  int R = (int)(rem / 5120);
  R = (R / 4096) * 4096;
  if (R > 16384) R = 16384;
  if (R < 4096) R = 4096;
  const int nch = 65536 / R;
  unsigned short* bufA = (unsigned short*)((char*)d_ws + wbytes);
  unsigned short* bufB = bufA + (size_t)R * 512;

  transpose_kern<<<dim3(1536 / 32, 512 / 32), 256, 0, stream>>>(qkv_w, qkvT, 512, 1536);
  transpose_kern<<<dim3(512 / 32, 512 / 32), 256, 0, stream>>>(proj_w, projT, 512, 512);
  transpose_kern<<<dim3(2048 / 32, 512 / 32), 256, 0, stream>>>(fc1_w, fc1T, 512, 2048);
  transpose_kern<<<dim3(512 / 32, 2048 / 32), 256, 0, stream>>>(fc2_w, fc2T, 2048, 512);

  // merged per-chunk pipeline: keeps the chunk's x2 (16 MiB f32) L3-resident
  for (int cb = 0; cb < nch; ++cb) {
    ln_kern<<<R, 256, 0, stream>>>(x, n1g, n1b, bufA, cb * R, 1);
    gemm_bt<0><<<dim3(12, R / 128), 256, 0, stream>>>(bufA, qkvT, qkv_b, bufB, nullptr,
                                                      R, 1536, 512, 0);
    attn_kern<<<(R / 64) * 16, 256, 0, stream>>>(bufB, relb, bufA);
    gemm_bt<2><<<dim3(4, R / 128), 256, 0, stream>>>(bufA, projT, proj_b, x2, x,
                                                     R, 512, 512, cb * R);
    ln_kern<<<R, 256, 0, stream>>>(x2, n2g, n2b, bufA, cb * R, 0);
    gemm_bt<1><<<dim3(16, R / 128), 256, 0, stream>>>(bufA, fc1T, fc1_b, bufB, nullptr,
                                                      R, 2048, 512, 0);
    gemm_bt<3><<<dim3(4, R / 128), 256, 0, stream>>>(bufB, fc2T, fc2_b,
                                                     x2 + (size_t)cb * R * 512,
                                                     x2 + (size_t)cb * R * 512,
                                                     R, 512, 2048, 0);
  }
}

// Round 7
// 1137.839 us; speedup vs baseline: 1.2246x; 1.0611x over previous
//
#include <hip/hip_runtime.h>
#include <stdint.h>

typedef __attribute__((ext_vector_type(8))) short short8;
typedef __attribute__((ext_vector_type(4))) float floatx4;

__device__ __forceinline__ float bf2f(unsigned short h) {
  union { unsigned int u; float f; } v; v.u = ((unsigned int)h) << 16; return v.f;
}
__device__ __forceinline__ unsigned short f2bf(float f) {
  union { float f; unsigned int u; } v; v.f = f;
  unsigned int r = v.u + 0x7fffu + ((v.u >> 16) & 1u);
  return (unsigned short)(r >> 16);
}

__device__ __forceinline__ void gll16(const void* g, void* l) {
  __builtin_amdgcn_global_load_lds((const __attribute__((address_space(1))) unsigned int*)g,
                                   (__attribute__((address_space(3))) unsigned int*)l, 16, 0, 0);
}

// DPP row_ror:K (rotation within each 16-lane row) — VALU pipe.
template <int K>
__device__ __forceinline__ float rorf(float x) {
  return __int_as_float(__builtin_amdgcn_update_dpp(0, __float_as_int(x), 0x120 + K, 0xF, 0xF, false));
}
__device__ __forceinline__ float grpsum16(float v) {
  v += rorf<1>(v); v += rorf<2>(v); v += rorf<4>(v); v += rorf<8>(v);
  return v;
}
// ds_swizzle xor-16 (BitMode: xor<<10 | and 0x1F)
__device__ __forceinline__ float swz16(float x) {
  return __int_as_float(__builtin_amdgcn_ds_swizzle(__float_as_int(x), 0x401F));
}

// ------------- weight transpose+convert: in f32 (K,N) -> out bf16 (N,K) -------------
__global__ __launch_bounds__(256) void transpose_kern(const float* __restrict__ in,
                                                      unsigned short* __restrict__ out,
                                                      int K, int N) {
  __shared__ float tile[32][33];
  const int tx = threadIdx.x & 31, ty = threadIdx.x >> 5;
  const int n0 = blockIdx.x * 32, k0 = blockIdx.y * 32;
#pragma unroll
  for (int i = 0; i < 4; ++i)
    tile[ty + 8 * i][tx] = in[(size_t)(k0 + ty + 8 * i) * N + n0 + tx];
  __syncthreads();
#pragma unroll
  for (int i = 0; i < 4; ++i)
    out[(size_t)(n0 + ty + 8 * i) * K + k0 + tx] = f2bf(tile[tx][ty + 8 * i]);
}

// ------------- LayerNorm f32 -> bf16 (+ optional roll/window-partition scatter) -------------
__global__ __launch_bounds__(256) void ln_kern(const float* __restrict__ x,
                                               const float* __restrict__ g,
                                               const float* __restrict__ b,
                                               unsigned short* __restrict__ out,
                                               int tokenBase, int scatter) {
  const int t = tokenBase + blockIdx.x;
  const float* xr = x + (size_t)t * 512;
  const int c = threadIdx.x * 2;
  const float x0 = xr[c], x1 = xr[c + 1];
  float s = x0 + x1, s2 = x0 * x0 + x1 * x1;
#pragma unroll
  for (int off = 32; off; off >>= 1) {
    s += __shfl_xor(s, off, 64);
    s2 += __shfl_xor(s2, off, 64);
  }
  __shared__ float red[2][4];
  const int l = threadIdx.x & 63, wv = threadIdx.x >> 6;
  if (l == 0) { red[0][wv] = s; red[1][wv] = s2; }
  __syncthreads();
  s = red[0][0] + red[0][1] + red[0][2] + red[0][3];
  s2 = red[1][0] + red[1][1] + red[1][2] + red[1][3];
  const float mean = s * (1.0f / 512.0f);
  const float var = s2 * (1.0f / 512.0f) - mean * mean;
  const float rstd = rsqrtf(var + 1e-5f);
  const float y0 = (x0 - mean) * rstd * g[c] + b[c];
  const float y1 = (x1 - mean) * rstd * g[c + 1] + b[c + 1];
  int orow;
  if (scatter) {
    const int bb = t >> 12, rem = t & 4095, h = rem >> 6, w = rem & 63;
    const int hp = (h + 60) & 63, wp = (w + 60) & 63;
    const int wh = hp >> 3, i = hp & 7, ww = wp >> 3, j = wp & 7;
    const int rg = ((bb << 6) + (wh << 3) + ww) * 64 + (i << 3) + j;
    orow = rg - tokenBase;
  } else {
    orow = blockIdx.x;
  }
  const unsigned int o = (unsigned int)f2bf(y0) | ((unsigned int)f2bf(y1) << 16);
  *(unsigned int*)(out + (size_t)orow * 512 + c) = o;
}

// ------------- GEMM: C = A(MxK,bf16) * Bt(NxK,bf16)^T + bias(f32), fused epilogues -------------
// BK=64, LDS rows 128B, XOR-swizzled slots: LDS slot s holds global 16B-slot s^(row&7).
template <int EPI>
__global__ __launch_bounds__(256) void gemm_bt(const unsigned short* __restrict__ A,
                                               const unsigned short* __restrict__ Bt,
                                               const float* __restrict__ bias,
                                               void* __restrict__ outv,
                                               const float* __restrict__ res,
                                               int M, int N, int K, int rowBase) {
  __shared__ unsigned short As[128][64];
  __shared__ unsigned short Bs[128][64];
  const int tid = threadIdx.x;
  const int l = tid & 63, wv = tid >> 6;
  const int wm = wv >> 1, wn = wv & 1;
  const int bm = blockIdx.y * 128, bn = blockIdx.x * 128;

  floatx4 acc[4][4];
#pragma unroll
  for (int i = 0; i < 4; ++i)
#pragma unroll
    for (int j = 0; j < 4; ++j) acc[i][j] = {0.0f, 0.0f, 0.0f, 0.0f};

  // staging: per gll16, 64 lanes cover 8 rows x 128B; lane row-off = l>>3, slot = l&7.
  // global slot pre-swizzled so LDS slot (l&7) holds global slot (l&7)^(row&7); row&7 = l>>3.
  const int srow = l >> 3;
  const int sslot = ((l & 7) ^ (l >> 3)) * 8;   // shorts

  for (int k0 = 0; k0 < K; k0 += 64) {
#pragma unroll
    for (int tt = 0; tt < 4; ++tt) {
      const int r = wv * 32 + tt * 8;
      gll16(A + (size_t)(bm + r + srow) * K + k0 + sslot, &As[r][0]);
      gll16(Bt + (size_t)(bn + r + srow) * K + k0 + sslot, &Bs[r][0]);
    }
    __syncthreads();
#pragma unroll
    for (int kh = 0; kh < 2; ++kh) {
      // read slot for global k-slot (kh*4 + l>>4): XOR with row&7 = l&7
      const int rslot = ((kh * 4 + (l >> 4)) ^ (l & 7)) * 8;
      short8 af[4], bfr[4];
#pragma unroll
      for (int mt = 0; mt < 4; ++mt)
        af[mt] = *(const short8*)&As[wm * 64 + mt * 16 + (l & 15)][rslot];
#pragma unroll
      for (int nt = 0; nt < 4; ++nt)
        bfr[nt] = *(const short8*)&Bs[wn * 64 + nt * 16 + (l & 15)][rslot];
#pragma unroll
      for (int mt = 0; mt < 4; ++mt)
#pragma unroll
        for (int nt = 0; nt < 4; ++nt)
          acc[mt][nt] = __builtin_amdgcn_mfma_f32_16x16x32_bf16(af[mt], bfr[nt], acc[mt][nt], 0, 0, 0);
    }
    __syncthreads();
  }

#pragma unroll
  for (int mt = 0; mt < 4; ++mt) {
#pragma unroll
    for (int nt = 0; nt < 4; ++nt) {
      const int gcol = bn + wn * 64 + nt * 16 + (l & 15);
      const float bv = bias[gcol];
#pragma unroll
      for (int r = 0; r < 4; ++r) {
        const int grow = bm + wm * 64 + mt * 16 + (l >> 4) * 4 + r;
        float v = acc[mt][nt][r] + bv;
        if (EPI == 1) {
          // tanh-GELU: v*sigmoid(2*sqrt(2/pi)*(v+0.044715 v^3)); |err|<~2e-3, << threshold
          const float t2 = v * (1.5957691216057308f + 0.071354816222f * v * v);
          v = v * (1.0f / (1.0f + __expf(-t2)));
        }
        if (EPI == 2) {
          const int rg = rowBase + grow;
          const int bw = rg >> 6, n = rg & 63;
          const int bb = bw >> 6, wi = bw & 63;
          const int i = n >> 3, j = n & 7;
          const int hp = ((wi >> 3) << 3) + i;
          const int wp = ((wi & 7) << 3) + j;
          const int h = (hp + 4) & 63, w = (wp + 4) & 63;
          const size_t t = (size_t)((bb << 12) + (h << 6) + w);
          ((float*)outv)[t * 512 + gcol] = v + res[t * 512 + gcol];
        } else if (EPI == 3) {
          ((float*)outv)[(size_t)grow * 512 + gcol] = v + res[(size_t)grow * 512 + gcol];
        } else {
          ((unsigned short*)outv)[(size_t)grow * (size_t)N + gcol] = f2bf(v);
        }
      }
    }
  }
}

// ------------- attention per (window, head): QK^T + bias, top-48 via radix-select, P@V -------------
__global__ __launch_bounds__(256) void attn_kern(const unsigned short* __restrict__ qkv,
                                                 const float* __restrict__ relb,
                                                 unsigned short* __restrict__ attnout) {
  __shared__ float Ss[64][66];            // scores f32; row head reused for bf16 P after consumption
  __shared__ unsigned short VT[32][66];   // V transposed [d][key]
  __shared__ float biasL[240];

  const int u = blockIdx.x;
  const int bwl = u >> 4, head = u & 15;
  const int tid = threadIdx.x;
  const int l = tid & 63, wv = tid >> 6;

  {
    const int row = tid >> 2, d0 = (tid & 3) * 8;
    short8 v8 = *(const short8*)(qkv + (size_t)(bwl * 64 + row) * 1536 + 1024 + head * 32 + d0);
#pragma unroll
    for (int j = 0; j < 8; ++j) VT[d0 + j][row] = (unsigned short)v8[j];
  }
  if (tid < 225) biasL[tid] = relb[tid * 16 + head];
  __syncthreads();   // VT/biasL visible to all waves

  {
    short8 a = *(const short8*)(qkv + (size_t)(bwl * 64 + wv * 16 + (l & 15)) * 1536 +
                                head * 32 + (l >> 4) * 8);
    const int n0 = wv * 16 + (l >> 4) * 4;
    const int m0 = l & 15;
    const int ibase = ((n0 >> 3) - (m0 >> 3) + 7) * 15 + ((n0 & 7) - (m0 & 7) + 7);
#pragma unroll
    for (int nt = 0; nt < 4; ++nt) {
      short8 bfr = *(const short8*)(qkv + (size_t)(bwl * 64 + nt * 16 + (l & 15)) * 1536 + 512 +
                                    head * 32 + (l >> 4) * 8);
      floatx4 z = {0.0f, 0.0f, 0.0f, 0.0f};
      floatx4 d = __builtin_amdgcn_mfma_f32_16x16x32_bf16(a, bfr, z, 0, 0, 0);
#pragma unroll
      for (int r = 0; r < 4; ++r)
        Ss[n0 + r][m0 + nt * 16] = fmaf(d[r], 0.17677669529663689f, biasL[ibase + r - 30 * nt]);
    }
  }

  // per-row top-48 + softmax; threshold via MSB-first radix bisection (SALU count/select).
  float* srow_base = &Ss[wv * 16][0];
#pragma unroll 1
  for (int rr = 0; rr < 16; ++rr) {
    const float own = srow_base[rr * 66 + l];
    const unsigned int uo = __float_as_uint(own);
    const unsigned int mapped = uo ^ ((unsigned int)((int)uo >> 31) | 0x80000000u);
    unsigned int p = 0;
#pragma unroll 1
    for (int b = 31; b >= 0; --b) {
      const unsigned int cand = p | (1u << b);
      const int c = __popcll(__ballot(mapped >= cand));
      if (c >= 48) {
        p = cand;
        if (c == 48) break;   // exactly 48 kept — threshold found
      }
    }
    const float tf = __uint_as_float((p & 0x80000000u) ? (p ^ 0x80000000u) : ~p);
    const float e = (mapped >= p) ? __expf(own - tf) : 0.0f;
    float zs = grpsum16(e);
    zs += swz16(zs);
    zs += __shfl_xor(zs, 32, 64);
    ((unsigned short*)(srow_base + rr * 66))[l] = f2bf(e * __builtin_amdgcn_rcpf(zs));
  }

  // out = P (64x64) @ V (64x32); P rows are wave-private
  {
    floatx4 acc[2];
    acc[0] = {0.0f, 0.0f, 0.0f, 0.0f};
    acc[1] = {0.0f, 0.0f, 0.0f, 0.0f};
#pragma unroll
    for (int kh = 0; kh < 2; ++kh) {
      short8 pa = *(const short8*)((const unsigned short*)&Ss[wv * 16 + (l & 15)][0] +
                                   kh * 32 + (l >> 4) * 8);
#pragma unroll
      for (int nt = 0; nt < 2; ++nt) {
        short8 vb = *(const short8*)&VT[nt * 16 + (l & 15)][kh * 32 + (l >> 4) * 8];
        acc[nt] = __builtin_amdgcn_mfma_f32_16x16x32_bf16(pa, vb, acc[nt], 0, 0, 0);
      }
    }
#pragma unroll
    for (int nt = 0; nt < 2; ++nt)
#pragma unroll
      for (int r = 0; r < 4; ++r) {
        const int n = wv * 16 + (l >> 4) * 4 + r;
        const int dcol = nt * 16 + (l & 15);
        attnout[(size_t)(bwl * 64 + n) * 512 + head * 32 + dcol] = f2bf(acc[nt][r]);
      }
  }
}

// ---------------- launcher ----------------
extern "C" void kernel_launch(void* const* d_in, const int* in_sizes, int n_in,
                              void* d_out, int out_size, void* d_ws, size_t ws_size,
                              hipStream_t stream) {
  (void)in_sizes; (void)n_in; (void)out_size;
  const float* x      = (const float*)d_in[0];
  const float* n1g    = (const float*)d_in[1];
  const float* n1b    = (const float*)d_in[2];
  const float* qkv_w  = (const float*)d_in[3];
  const float* qkv_b  = (const float*)d_in[4];
  const float* relb   = (const float*)d_in[5];
  const float* proj_w = (const float*)d_in[6];
  const float* proj_b = (const float*)d_in[7];
  const float* n2g    = (const float*)d_in[8];
  const float* n2b    = (const float*)d_in[9];
  const float* fc1_w  = (const float*)d_in[10];
  const float* fc1_b  = (const float*)d_in[11];
  const float* fc2_w  = (const float*)d_in[12];
  const float* fc2_b  = (const float*)d_in[13];
  float* x2 = (float*)d_out;   // post-attention residual state lives in d_out (f32)

  unsigned short* qkvT  = (unsigned short*)d_ws;
  unsigned short* projT = qkvT + 1536 * 512;
  unsigned short* fc1T  = projT + 512 * 512;
  unsigned short* fc2T  = fc1T + 2048 * 512;
  const size_t wbytes = (size_t)(1536 * 512 + 512 * 512 + 2048 * 512 + 512 * 2048) * 2;
  size_t rem = ws_size > wbytes ? ws_size - wbytes : 0;
  int R = (int)(rem / 5120);
  R = (R / 4096) * 4096;
  if (R > 16384) R = 16384;
  if (R < 4096) R = 4096;
  const int nch = 65536 / R;
  unsigned short* bufA = (unsigned short*)((char*)d_ws + wbytes);
  unsigned short* bufB = bufA + (size_t)R * 512;

  transpose_kern<<<dim3(1536 / 32, 512 / 32), 256, 0, stream>>>(qkv_w, qkvT, 512, 1536);
  transpose_kern<<<dim3(512 / 32, 512 / 32), 256, 0, stream>>>(proj_w, projT, 512, 512);
  transpose_kern<<<dim3(2048 / 32, 512 / 32), 256, 0, stream>>>(fc1_w, fc1T, 512, 2048);
  transpose_kern<<<dim3(512 / 32, 2048 / 32), 256, 0, stream>>>(fc2_w, fc2T, 2048, 512);

  // merged per-chunk pipeline: keeps the chunk's x2 (16 MiB f32) L3-resident
  for (int cb = 0; cb < nch; ++cb) {
    ln_kern<<<R, 256, 0, stream>>>(x, n1g, n1b, bufA, cb * R, 1);
    gemm_bt<0><<<dim3(12, R / 128), 256, 0, stream>>>(bufA, qkvT, qkv_b, bufB, nullptr,
                                                      R, 1536, 512, 0);
    attn_kern<<<(R / 64) * 16, 256, 0, stream>>>(bufB, relb, bufA);
    gemm_bt<2><<<dim3(4, R / 128), 256, 0, stream>>>(bufA, projT, proj_b, x2, x,
                                                     R, 512, 512, cb * R);
    ln_kern<<<R, 256, 0, stream>>>(x2, n2g, n2b, bufA, cb * R, 0);
    gemm_bt<1><<<dim3(16, R / 128), 256, 0, stream>>>(bufA, fc1T, fc1_b, bufB, nullptr,
                                                      R, 2048, 512, 0);
    gemm_bt<3><<<dim3(4, R / 128), 256, 0, stream>>>(bufB, fc2T, fc2_b,
                                                     x2 + (size_t)cb * R * 512,
                                                     x2 + (size_t)cb * R * 512,
                                                     R, 512, 2048, 0);
  }
}

// Round 8
// 1113.769 us; speedup vs baseline: 1.2511x; 1.0216x over previous
//
#include <hip/hip_runtime.h>
#include <stdint.h>

typedef __attribute__((ext_vector_type(8))) short short8;
typedef __attribute__((ext_vector_type(4))) float floatx4;

__device__ __forceinline__ float bf2f(unsigned short h) {
  union { unsigned int u; float f; } v; v.u = ((unsigned int)h) << 16; return v.f;
}
__device__ __forceinline__ unsigned short f2bf(float f) {
  union { float f; unsigned int u; } v; v.f = f;
  unsigned int r = v.u + 0x7fffu + ((v.u >> 16) & 1u);
  return (unsigned short)(r >> 16);
}

__device__ __forceinline__ void gll16(const void* g, void* l) {
  __builtin_amdgcn_global_load_lds((const __attribute__((address_space(1))) unsigned int*)g,
                                   (__attribute__((address_space(3))) unsigned int*)l, 16, 0, 0);
}

// DPP row_ror:K (rotation within each 16-lane row) — VALU pipe.
template <int K>
__device__ __forceinline__ float rorf(float x) {
  return __int_as_float(__builtin_amdgcn_update_dpp(0, __float_as_int(x), 0x120 + K, 0xF, 0xF, false));
}
__device__ __forceinline__ float grpsum16(float v) {
  v += rorf<1>(v); v += rorf<2>(v); v += rorf<4>(v); v += rorf<8>(v);
  return v;
}
// ds_swizzle xor-16 (BitMode: xor<<10 | and 0x1F)
__device__ __forceinline__ float swz16(float x) {
  return __int_as_float(__builtin_amdgcn_ds_swizzle(__float_as_int(x), 0x401F));
}

// ------------- weight transpose+convert: in f32 (K,N) -> out bf16 (N,K) -------------
__global__ __launch_bounds__(256) void transpose_kern(const float* __restrict__ in,
                                                      unsigned short* __restrict__ out,
                                                      int K, int N) {
  __shared__ float tile[32][33];
  const int tx = threadIdx.x & 31, ty = threadIdx.x >> 5;
  const int n0 = blockIdx.x * 32, k0 = blockIdx.y * 32;
#pragma unroll
  for (int i = 0; i < 4; ++i)
    tile[ty + 8 * i][tx] = in[(size_t)(k0 + ty + 8 * i) * N + n0 + tx];
  __syncthreads();
#pragma unroll
  for (int i = 0; i < 4; ++i)
    out[(size_t)(n0 + ty + 8 * i) * K + k0 + tx] = f2bf(tile[tx][ty + 8 * i]);
}

// ------------- LayerNorm f32 -> bf16 (+ optional roll/window-partition scatter) -------------
__global__ __launch_bounds__(256) void ln_kern(const float* __restrict__ x,
                                               const float* __restrict__ g,
                                               const float* __restrict__ b,
                                               unsigned short* __restrict__ out,
                                               int tokenBase, int scatter) {
  const int t = tokenBase + blockIdx.x;
  const float* xr = x + (size_t)t * 512;
  const int c = threadIdx.x * 2;
  const float x0 = xr[c], x1 = xr[c + 1];
  float s = x0 + x1, s2 = x0 * x0 + x1 * x1;
#pragma unroll
  for (int off = 32; off; off >>= 1) {
    s += __shfl_xor(s, off, 64);
    s2 += __shfl_xor(s2, off, 64);
  }
  __shared__ float red[2][4];
  const int l = threadIdx.x & 63, wv = threadIdx.x >> 6;
  if (l == 0) { red[0][wv] = s; red[1][wv] = s2; }
  __syncthreads();
  s = red[0][0] + red[0][1] + red[0][2] + red[0][3];
  s2 = red[1][0] + red[1][1] + red[1][2] + red[1][3];
  const float mean = s * (1.0f / 512.0f);
  const float var = s2 * (1.0f / 512.0f) - mean * mean;
  const float rstd = rsqrtf(var + 1e-5f);
  const float y0 = (x0 - mean) * rstd * g[c] + b[c];
  const float y1 = (x1 - mean) * rstd * g[c + 1] + b[c + 1];
  int orow;
  if (scatter) {
    const int bb = t >> 12, rem = t & 4095, h = rem >> 6, w = rem & 63;
    const int hp = (h + 60) & 63, wp = (w + 60) & 63;
    const int wh = hp >> 3, i = hp & 7, ww = wp >> 3, j = wp & 7;
    const int rg = ((bb << 6) + (wh << 3) + ww) * 64 + (i << 3) + j;
    orow = rg - tokenBase;
  } else {
    orow = blockIdx.x;
  }
  const unsigned int o = (unsigned int)f2bf(y0) | ((unsigned int)f2bf(y1) << 16);
  *(unsigned int*)(out + (size_t)orow * 512 + c) = o;
}

// ------------- GEMM: C = A(MxK,bf16) * Bt(NxK,bf16)^T + bias(f32), fused epilogues -------------
// BK=64, double-buffered LDS, ONE barrier per K-step, prefetch-before-compute (T3 minimum).
// XOR-swizzled slots: LDS slot s holds global 16B-slot s^(row&7) (pre-swizzled global source).
template <int EPI>
__global__ __launch_bounds__(256) void gemm_bt(const unsigned short* __restrict__ A,
                                               const unsigned short* __restrict__ Bt,
                                               const float* __restrict__ bias,
                                               void* __restrict__ outv,
                                               const float* __restrict__ res,
                                               int M, int N, int K, int rowBase) {
  __shared__ unsigned short As[2][128][64];
  __shared__ unsigned short Bs[2][128][64];
  const int tid = threadIdx.x;
  const int l = tid & 63, wv = tid >> 6;
  const int wm = wv >> 1, wn = wv & 1;
  const int bm = blockIdx.y * 128, bn = blockIdx.x * 128;

  floatx4 acc[4][4];
#pragma unroll
  for (int i = 0; i < 4; ++i)
#pragma unroll
    for (int j = 0; j < 4; ++j) acc[i][j] = {0.0f, 0.0f, 0.0f, 0.0f};

  // staging: per gll16, 64 lanes cover 8 rows x 128B; lane row-off = l>>3, slot = l&7.
  const int srow = l >> 3;
  const int sslot = ((l & 7) ^ (l >> 3)) * 8;   // shorts; inverse-swizzled global source

  const unsigned short* Abase = A + (size_t)(bm + srow) * K + sslot;
  const unsigned short* Bbase = Bt + (size_t)(bn + srow) * K + sslot;

#define STAGE(bb, k0)                                                        \
  {                                                                          \
    _Pragma("unroll")                                                        \
    for (int tt = 0; tt < 4; ++tt) {                                         \
      const int r = wv * 32 + tt * 8;                                        \
      gll16(Abase + (size_t)r * K + (k0), &As[bb][r][0]);                    \
      gll16(Bbase + (size_t)r * K + (k0), &Bs[bb][r][0]);                    \
    }                                                                        \
  }

  STAGE(0, 0);
  __syncthreads();           // drains vmcnt(0): tile 0 resident

  const int nt = K >> 6;
  int cur = 0;
#pragma unroll 1
  for (int t = 0; t < nt; ++t) {
    if (t + 1 < nt) STAGE(cur ^ 1, (t + 1) * 64);   // prefetch overlaps compute below
#pragma unroll
    for (int kh = 0; kh < 2; ++kh) {
      const int rslot = ((kh * 4 + (l >> 4)) ^ (l & 7)) * 8;
      short8 af[4], bfr[4];
#pragma unroll
      for (int mt = 0; mt < 4; ++mt)
        af[mt] = *(const short8*)&As[cur][wm * 64 + mt * 16 + (l & 15)][rslot];
#pragma unroll
      for (int nt2 = 0; nt2 < 4; ++nt2)
        bfr[nt2] = *(const short8*)&Bs[cur][wn * 64 + nt2 * 16 + (l & 15)][rslot];
#pragma unroll
      for (int mt = 0; mt < 4; ++mt)
#pragma unroll
        for (int nt2 = 0; nt2 < 4; ++nt2)
          acc[mt][nt2] = __builtin_amdgcn_mfma_f32_16x16x32_bf16(af[mt], bfr[nt2], acc[mt][nt2], 0, 0, 0);
    }
    if (t + 1 < nt) {
      __syncthreads();       // single barrier/K-step: prefetch landed + cur fully consumed
      cur ^= 1;
    }
  }
#undef STAGE

#pragma unroll
  for (int mt = 0; mt < 4; ++mt) {
#pragma unroll
    for (int nt2 = 0; nt2 < 4; ++nt2) {
      const int gcol = bn + wn * 64 + nt2 * 16 + (l & 15);
      const float bv = bias[gcol];
#pragma unroll
      for (int r = 0; r < 4; ++r) {
        const int grow = bm + wm * 64 + mt * 16 + (l >> 4) * 4 + r;
        float v = acc[mt][nt2][r] + bv;
        if (EPI == 1) {
          // tanh-GELU: v*sigmoid(2*sqrt(2/pi)*(v+0.044715 v^3)); |err|<~2e-3, << threshold
          const float t2 = v * (1.5957691216057308f + 0.071354816222f * v * v);
          v = v * (1.0f / (1.0f + __expf(-t2)));
        }
        if (EPI == 2) {
          const int rg = rowBase + grow;
          const int bw = rg >> 6, n = rg & 63;
          const int bb = bw >> 6, wi = bw & 63;
          const int i = n >> 3, j = n & 7;
          const int hp = ((wi >> 3) << 3) + i;
          const int wp = ((wi & 7) << 3) + j;
          const int h = (hp + 4) & 63, w = (wp + 4) & 63;
          const size_t t = (size_t)((bb << 12) + (h << 6) + w);
          ((float*)outv)[t * 512 + gcol] = v + res[t * 512 + gcol];
        } else if (EPI == 3) {
          ((float*)outv)[(size_t)grow * 512 + gcol] = v + res[(size_t)grow * 512 + gcol];
        } else {
          ((unsigned short*)outv)[(size_t)grow * (size_t)N + gcol] = f2bf(v);
        }
      }
    }
  }
}

// ------------- attention per (window, head): QK^T + bias, top-48 via radix-select, P@V -------------
__global__ __launch_bounds__(256) void attn_kern(const unsigned short* __restrict__ qkv,
                                                 const float* __restrict__ relb,
                                                 unsigned short* __restrict__ attnout) {
  __shared__ float Ss[64][66];            // scores f32; row head reused for bf16 P after consumption
  __shared__ unsigned short VT[32][66];   // V transposed [d][key]
  __shared__ float biasL[240];

  const int u = blockIdx.x;
  const int bwl = u >> 4, head = u & 15;
  const int tid = threadIdx.x;
  const int l = tid & 63, wv = tid >> 6;

  {
    const int row = tid >> 2, d0 = (tid & 3) * 8;
    short8 v8 = *(const short8*)(qkv + (size_t)(bwl * 64 + row) * 1536 + 1024 + head * 32 + d0);
#pragma unroll
    for (int j = 0; j < 8; ++j) VT[d0 + j][row] = (unsigned short)v8[j];
  }
  if (tid < 225) biasL[tid] = relb[tid * 16 + head];
  __syncthreads();   // VT/biasL visible to all waves

  {
    short8 a = *(const short8*)(qkv + (size_t)(bwl * 64 + wv * 16 + (l & 15)) * 1536 +
                                head * 32 + (l >> 4) * 8);
    const int n0 = wv * 16 + (l >> 4) * 4;
    const int m0 = l & 15;
    const int ibase = ((n0 >> 3) - (m0 >> 3) + 7) * 15 + ((n0 & 7) - (m0 & 7) + 7);
#pragma unroll
    for (int nt = 0; nt < 4; ++nt) {
      short8 bfr = *(const short8*)(qkv + (size_t)(bwl * 64 + nt * 16 + (l & 15)) * 1536 + 512 +
                                    head * 32 + (l >> 4) * 8);
      floatx4 z = {0.0f, 0.0f, 0.0f, 0.0f};
      floatx4 d = __builtin_amdgcn_mfma_f32_16x16x32_bf16(a, bfr, z, 0, 0, 0);
#pragma unroll
      for (int r = 0; r < 4; ++r)
        Ss[n0 + r][m0 + nt * 16] = fmaf(d[r], 0.17677669529663689f, biasL[ibase + r - 30 * nt]);
    }
  }

  // per-row top-48 + softmax; threshold via MSB-first radix bisection (SALU count/select).
  float* srow_base = &Ss[wv * 16][0];
#pragma unroll 1
  for (int rr = 0; rr < 16; ++rr) {
    const float own = srow_base[rr * 66 + l];
    const unsigned int uo = __float_as_uint(own);
    const unsigned int mapped = uo ^ ((unsigned int)((int)uo >> 31) | 0x80000000u);
    unsigned int p = 0;
#pragma unroll 1
    for (int b = 31; b >= 0; --b) {
      const unsigned int cand = p | (1u << b);
      const int c = __popcll(__ballot(mapped >= cand));
      if (c >= 48) {
        p = cand;
        if (c == 48) break;   // exactly 48 kept — threshold found
      }
    }
    const float tf = __uint_as_float((p & 0x80000000u) ? (p ^ 0x80000000u) : ~p);
    const float e = (mapped >= p) ? __expf(own - tf) : 0.0f;
    float zs = grpsum16(e);
    zs += swz16(zs);
    zs += __shfl_xor(zs, 32, 64);
    ((unsigned short*)(srow_base + rr * 66))[l] = f2bf(e * __builtin_amdgcn_rcpf(zs));
  }

  // out = P (64x64) @ V (64x32); P rows are wave-private
  {
    floatx4 acc[2];
    acc[0] = {0.0f, 0.0f, 0.0f, 0.0f};
    acc[1] = {0.0f, 0.0f, 0.0f, 0.0f};
#pragma unroll
    for (int kh = 0; kh < 2; ++kh) {
      short8 pa = *(const short8*)((const unsigned short*)&Ss[wv * 16 + (l & 15)][0] +
                                   kh * 32 + (l >> 4) * 8);
#pragma unroll
      for (int nt = 0; nt < 2; ++nt) {
        short8 vb = *(const short8*)&VT[nt * 16 + (l & 15)][kh * 32 + (l >> 4) * 8];
        acc[nt] = __builtin_amdgcn_mfma_f32_16x16x32_bf16(pa, vb, acc[nt], 0, 0, 0);
      }
    }
#pragma unroll
    for (int nt = 0; nt < 2; ++nt)
#pragma unroll
      for (int r = 0; r < 4; ++r) {
        const int n = wv * 16 + (l >> 4) * 4 + r;
        const int dcol = nt * 16 + (l & 15);
        attnout[(size_t)(bwl * 64 + n) * 512 + head * 32 + dcol] = f2bf(acc[nt][r]);
      }
  }
}

// ---------------- launcher ----------------
extern "C" void kernel_launch(void* const* d_in, const int* in_sizes, int n_in,
                              void* d_out, int out_size, void* d_ws, size_t ws_size,
                              hipStream_t stream) {
  (void)in_sizes; (void)n_in; (void)out_size;
  const float* x      = (const float*)d_in[0];
  const float* n1g    = (const float*)d_in[1];
  const float* n1b    = (const float*)d_in[2];
  const float* qkv_w  = (const float*)d_in[3];
  const float* qkv_b  = (const float*)d_in[4];
  const float* relb   = (const float*)d_in[5];
  const float* proj_w = (const float*)d_in[6];
  const float* proj_b = (const float*)d_in[7];
  const float* n2g    = (const float*)d_in[8];
  const float* n2b    = (const float*)d_in[9];
  const float* fc1_w  = (const float*)d_in[10];
  const float* fc1_b  = (const float*)d_in[11];
  const float* fc2_w  = (const float*)d_in[12];
  const float* fc2_b  = (const float*)d_in[13];
  float* x2 = (float*)d_out;   // post-attention residual state lives in d_out (f32)

  unsigned short* qkvT  = (unsigned short*)d_ws;
  unsigned short* projT = qkvT + 1536 * 512;
  unsigned short* fc1T  = projT + 512 * 512;
  unsigned short* fc2T  = fc1T + 2048 * 512;
  const size_t wbytes = (size_t)(1536 * 512 + 512 * 512 + 2048 * 512 + 512 * 2048) * 2;
  size_t rem = ws_size > wbytes ? ws_size - wbytes : 0;
  int R = (int)(rem / 5120);
  R = (R / 4096) * 4096;
  if (R > 16384) R = 16384;
  if (R < 4096) R = 4096;
  const int nch = 65536 / R;
  unsigned short* bufA = (unsigned short*)((char*)d_ws + wbytes);
  unsigned short* bufB = bufA + (size_t)R * 512;

  transpose_kern<<<dim3(1536 / 32, 512 / 32), 256, 0, stream>>>(qkv_w, qkvT, 512, 1536);
  transpose_kern<<<dim3(512 / 32, 512 / 32), 256, 0, stream>>>(proj_w, projT, 512, 512);
  transpose_kern<<<dim3(2048 / 32, 512 / 32), 256, 0, stream>>>(fc1_w, fc1T, 512, 2048);
  transpose_kern<<<dim3(512 / 32, 2048 / 32), 256, 0, stream>>>(fc2_w, fc2T, 2048, 512);

  // merged per-chunk pipeline: keeps the chunk's x2 (16 MiB f32) L3-resident
  for (int cb = 0; cb < nch; ++cb) {
    ln_kern<<<R, 256, 0, stream>>>(x, n1g, n1b, bufA, cb * R, 1);
    gemm_bt<0><<<dim3(12, R / 128), 256, 0, stream>>>(bufA, qkvT, qkv_b, bufB, nullptr,
                                                      R, 1536, 512, 0);
    attn_kern<<<(R / 64) * 16, 256, 0, stream>>>(bufB, relb, bufA);
    gemm_bt<2><<<dim3(4, R / 128), 256, 0, stream>>>(bufA, projT, proj_b, x2, x,
                                                     R, 512, 512, cb * R);
    ln_kern<<<R, 256, 0, stream>>>(x2, n2g, n2b, bufA, cb * R, 0);
    gemm_bt<1><<<dim3(16, R / 128), 256, 0, stream>>>(bufA, fc1T, fc1_b, bufB, nullptr,
                                                      R, 2048, 512, 0);
    gemm_bt<3><<<dim3(4, R / 128), 256, 0, stream>>>(bufB, fc2T, fc2_b,
                                                     x2 + (size_t)cb * R * 512,
                                                     x2 + (size_t)cb * R * 512,
                                                     R, 512, 2048, 0);
  }
}

// Round 9
// 1092.942 us; speedup vs baseline: 1.2749x; 1.0191x over previous
//
#include <hip/hip_runtime.h>
#include <stdint.h>

typedef __attribute__((ext_vector_type(8))) short short8;
typedef __attribute__((ext_vector_type(4))) float floatx4;

__device__ __forceinline__ float bf2f(unsigned short h) {
  union { unsigned int u; float f; } v; v.u = ((unsigned int)h) << 16; return v.f;
}
__device__ __forceinline__ unsigned short f2bf(float f) {
  union { float f; unsigned int u; } v; v.f = f;
  unsigned int r = v.u + 0x7fffu + ((v.u >> 16) & 1u);
  return (unsigned short)(r >> 16);
}

__device__ __forceinline__ void gll16(const void* g, void* l) {
  __builtin_amdgcn_global_load_lds((const __attribute__((address_space(1))) unsigned int*)g,
                                   (__attribute__((address_space(3))) unsigned int*)l, 16, 0, 0);
}

// DPP row_ror:K — VALU pipe.
template <int K>
__device__ __forceinline__ float rorf(float x) {
  return __int_as_float(__builtin_amdgcn_update_dpp(0, __float_as_int(x), 0x120 + K, 0xF, 0xF, false));
}
__device__ __forceinline__ float grpsum16(float v) {
  v += rorf<1>(v); v += rorf<2>(v); v += rorf<4>(v); v += rorf<8>(v);
  return v;
}
__device__ __forceinline__ float swz16(float x) {
  return __int_as_float(__builtin_amdgcn_ds_swizzle(__float_as_int(x), 0x401F));
}

// ------------- weight transpose+convert: in f32 (K,N) -> out bf16 (N,K) -------------
__global__ __launch_bounds__(256) void transpose_kern(const float* __restrict__ in,
                                                      unsigned short* __restrict__ out,
                                                      int K, int N) {
  __shared__ float tile[32][33];
  const int tx = threadIdx.x & 31, ty = threadIdx.x >> 5;
  const int n0 = blockIdx.x * 32, k0 = blockIdx.y * 32;
#pragma unroll
  for (int i = 0; i < 4; ++i)
    tile[ty + 8 * i][tx] = in[(size_t)(k0 + ty + 8 * i) * N + n0 + tx];
  __syncthreads();
#pragma unroll
  for (int i = 0; i < 4; ++i)
    out[(size_t)(n0 + ty + 8 * i) * K + k0 + tx] = f2bf(tile[tx][ty + 8 * i]);
}

// ------------- LayerNorm (f32 or bf16 in) -> bf16 (+ optional roll/window scatter) -------------
template <int BF16IN>
__global__ __launch_bounds__(256) void ln_kern(const void* __restrict__ xv,
                                               const float* __restrict__ g,
                                               const float* __restrict__ b,
                                               unsigned short* __restrict__ out,
                                               int tokenBase, int scatter) {
  const int t = tokenBase + blockIdx.x;
  const int c = threadIdx.x * 2;
  float x0, x1;
  if (BF16IN) {
    const unsigned int u = *(const unsigned int*)((const unsigned short*)xv + (size_t)t * 512 + c);
    x0 = bf2f((unsigned short)(u & 0xffffu)); x1 = bf2f((unsigned short)(u >> 16));
  } else {
    const float* xr = (const float*)xv + (size_t)t * 512;
    x0 = xr[c]; x1 = xr[c + 1];
  }
  float s = x0 + x1, s2 = x0 * x0 + x1 * x1;
#pragma unroll
  for (int off = 32; off; off >>= 1) {
    s += __shfl_xor(s, off, 64);
    s2 += __shfl_xor(s2, off, 64);
  }
  __shared__ float red[2][4];
  const int l = threadIdx.x & 63, wv = threadIdx.x >> 6;
  if (l == 0) { red[0][wv] = s; red[1][wv] = s2; }
  __syncthreads();
  s = red[0][0] + red[0][1] + red[0][2] + red[0][3];
  s2 = red[1][0] + red[1][1] + red[1][2] + red[1][3];
  const float mean = s * (1.0f / 512.0f);
  const float var = s2 * (1.0f / 512.0f) - mean * mean;
  const float rstd = rsqrtf(var + 1e-5f);
  const float y0 = (x0 - mean) * rstd * g[c] + b[c];
  const float y1 = (x1 - mean) * rstd * g[c + 1] + b[c + 1];
  int orow;
  if (scatter) {
    const int bb = t >> 12, rem = t & 4095, h = rem >> 6, w = rem & 63;
    const int hp = (h + 60) & 63, wp = (w + 60) & 63;
    const int wh = hp >> 3, i = hp & 7, ww = wp >> 3, j = wp & 7;
    const int rg = ((bb << 6) + (wh << 3) + ww) * 64 + (i << 3) + j;
    orow = rg - tokenBase;
  } else {
    orow = blockIdx.x;
  }
  const unsigned int o = (unsigned int)f2bf(y0) | ((unsigned int)f2bf(y1) << 16);
  *(unsigned int*)(out + (size_t)orow * 512 + c) = o;
}

// ------------- 128² GEMM: C = A*Bt^T + bias, fused epilogues (qkv/proj/fc2) -------------
// EPI 0: +bias -> bf16 out (stride N)
// EPI 2: +bias, window-reverse+roll scatter, += f32 res[token] -> BF16 out[token] (x2 state)
// EPI 3: +bias, += BF16 res[row] -> f32 out[row] (final output)
template <int EPI>
__global__ __launch_bounds__(256) void gemm_bt(const unsigned short* __restrict__ A,
                                               const unsigned short* __restrict__ Bt,
                                               const float* __restrict__ bias,
                                               void* __restrict__ outv,
                                               const void* __restrict__ resv,
                                               int M, int N, int K, int rowBase) {
  __shared__ unsigned short As[2][128][64];
  __shared__ unsigned short Bs[2][128][64];
  const int tid = threadIdx.x;
  const int l = tid & 63, wv = tid >> 6;
  const int wm = wv >> 1, wn = wv & 1;
  const int bm = blockIdx.y * 128, bn = blockIdx.x * 128;

  floatx4 acc[4][4];
#pragma unroll
  for (int i = 0; i < 4; ++i)
#pragma unroll
    for (int j = 0; j < 4; ++j) acc[i][j] = {0.0f, 0.0f, 0.0f, 0.0f};

  const int srow = l >> 3;
  const int sslot = ((l & 7) ^ (l >> 3)) * 8;
  const unsigned short* Abase = A + (size_t)(bm + srow) * K + sslot;
  const unsigned short* Bbase = Bt + (size_t)(bn + srow) * K + sslot;

#define STAGE(bb, k0)                                                        \
  {                                                                          \
    _Pragma("unroll")                                                        \
    for (int tt = 0; tt < 4; ++tt) {                                         \
      const int r = wv * 32 + tt * 8;                                        \
      gll16(Abase + (size_t)r * K + (k0), &As[bb][r][0]);                    \
      gll16(Bbase + (size_t)r * K + (k0), &Bs[bb][r][0]);                    \
    }                                                                        \
  }

  STAGE(0, 0);
  __syncthreads();

  const int ntl = K >> 6;
  int cur = 0;
#pragma unroll 1
  for (int t = 0; t < ntl; ++t) {
    if (t + 1 < ntl) STAGE(cur ^ 1, (t + 1) * 64);
#pragma unroll
    for (int kh = 0; kh < 2; ++kh) {
      const int rslot = ((kh * 4 + (l >> 4)) ^ (l & 7)) * 8;
      short8 af[4], bfr[4];
#pragma unroll
      for (int mt = 0; mt < 4; ++mt)
        af[mt] = *(const short8*)&As[cur][wm * 64 + mt * 16 + (l & 15)][rslot];
#pragma unroll
      for (int nt2 = 0; nt2 < 4; ++nt2)
        bfr[nt2] = *(const short8*)&Bs[cur][wn * 64 + nt2 * 16 + (l & 15)][rslot];
#pragma unroll
      for (int mt = 0; mt < 4; ++mt)
#pragma unroll
        for (int nt2 = 0; nt2 < 4; ++nt2)
          acc[mt][nt2] = __builtin_amdgcn_mfma_f32_16x16x32_bf16(af[mt], bfr[nt2], acc[mt][nt2], 0, 0, 0);
    }
    if (t + 1 < ntl) {
      __syncthreads();
      cur ^= 1;
    }
  }
#undef STAGE

#pragma unroll
  for (int mt = 0; mt < 4; ++mt) {
#pragma unroll
    for (int nt2 = 0; nt2 < 4; ++nt2) {
      const int gcol = bn + wn * 64 + nt2 * 16 + (l & 15);
      const float bv = bias[gcol];
#pragma unroll
      for (int r = 0; r < 4; ++r) {
        const int grow = bm + wm * 64 + mt * 16 + (l >> 4) * 4 + r;
        float v = acc[mt][nt2][r] + bv;
        if (EPI == 2) {
          const int rg = rowBase + grow;
          const int bw = rg >> 6, n = rg & 63;
          const int bb = bw >> 6, wi = bw & 63;
          const int i = n >> 3, j = n & 7;
          const int hp = ((wi >> 3) << 3) + i;
          const int wp = ((wi & 7) << 3) + j;
          const int h = (hp + 4) & 63, w = (wp + 4) & 63;
          const size_t t = (size_t)((bb << 12) + (h << 6) + w);
          // x2 state stored bf16: x2 = x + attn_proj
          ((unsigned short*)outv)[t * 512 + gcol] = f2bf(v + ((const float*)resv)[t * 512 + gcol]);
        } else if (EPI == 3) {
          // final: out(f32) = bf16(x2) + fc2
          ((float*)outv)[(size_t)grow * 512 + gcol] =
              v + bf2f(((const unsigned short*)resv)[(size_t)grow * 512 + gcol]);
        } else {
          ((unsigned short*)outv)[(size_t)grow * (size_t)N + gcol] = f2bf(v);
        }
      }
    }
  }
}

// ------------- 256² GEMM (8 waves, per-wave 128x64), EPI1 = exact-ish GELU -> bf16 (fc1) -------------
template <int EPI>
__global__ __launch_bounds__(512) void gemm256(const unsigned short* __restrict__ A,
                                               const unsigned short* __restrict__ Bt,
                                               const float* __restrict__ bias,
                                               unsigned short* __restrict__ out,
                                               int M, int N, int K) {
  __shared__ unsigned short As[2][256][64];
  __shared__ unsigned short Bs[2][256][64];
  const int tid = threadIdx.x;
  const int l = tid & 63, wid = tid >> 6;
  const int wm = wid >> 2, wn = wid & 3;        // 2 x 4 waves
  const int bm = blockIdx.y * 256, bn = blockIdx.x * 256;

  floatx4 acc[8][4];
#pragma unroll
  for (int i = 0; i < 8; ++i)
#pragma unroll
    for (int j = 0; j < 4; ++j) acc[i][j] = {0.0f, 0.0f, 0.0f, 0.0f};

  // staging: 512 thr x 16B = 64 rows per round; 4 rounds per matrix per K-tile
  const int srow = tid >> 3;                       // 0..63
  const int sslot = ((tid & 7) ^ (srow & 7)) * 8;  // inverse-swizzled global source
  const unsigned short* Ab = A + (size_t)(bm + srow) * K + sslot;
  const unsigned short* Bb = Bt + (size_t)(bn + srow) * K + sslot;
  const int ldsbase = wid * 8;                     // wave-uniform LDS dest row base

#define STG256(bb, k0)                                                          \
  {                                                                             \
    _Pragma("unroll")                                                           \
    for (int tt = 0; tt < 4; ++tt) {                                            \
      gll16(Ab + (size_t)(tt * 64) * K + (k0), &As[bb][tt * 64 + ldsbase][0]);  \
      gll16(Bb + (size_t)(tt * 64) * K + (k0), &Bs[bb][tt * 64 + ldsbase][0]);  \
    }                                                                           \
  }

  STG256(0, 0);
  __syncthreads();

  const int ntl = K >> 6;
  int cur = 0;
#pragma unroll 1
  for (int t = 0; t < ntl; ++t) {
    if (t + 1 < ntl) STG256(cur ^ 1, (t + 1) * 64);
#pragma unroll
    for (int kh = 0; kh < 2; ++kh) {
      const int rslot = ((kh * 4 + (l >> 4)) ^ (l & 7)) * 8;
      short8 af[8], bfr[4];
#pragma unroll
      for (int mt = 0; mt < 8; ++mt)
        af[mt] = *(const short8*)&As[cur][wm * 128 + mt * 16 + (l & 15)][rslot];
#pragma unroll
      for (int nt2 = 0; nt2 < 4; ++nt2)
        bfr[nt2] = *(const short8*)&Bs[cur][wn * 64 + nt2 * 16 + (l & 15)][rslot];
#pragma unroll
      for (int mt = 0; mt < 8; ++mt)
#pragma unroll
        for (int nt2 = 0; nt2 < 4; ++nt2)
          acc[mt][nt2] = __builtin_amdgcn_mfma_f32_16x16x32_bf16(af[mt], bfr[nt2], acc[mt][nt2], 0, 0, 0);
    }
    if (t + 1 < ntl) {
      __syncthreads();
      cur ^= 1;
    }
  }
#undef STG256

#pragma unroll
  for (int mt = 0; mt < 8; ++mt) {
#pragma unroll
    for (int nt2 = 0; nt2 < 4; ++nt2) {
      const int gcol = bn + wn * 64 + nt2 * 16 + (l & 15);
      const float bv = bias[gcol];
#pragma unroll
      for (int r = 0; r < 4; ++r) {
        const int grow = bm + wm * 128 + mt * 16 + (l >> 4) * 4 + r;
        float v = acc[mt][nt2][r] + bv;
        if (EPI == 1) {
          const float t2 = v * (1.5957691216057308f + 0.071354816222f * v * v);
          v = v * (1.0f / (1.0f + __expf(-t2)));
        }
        out[(size_t)grow * (size_t)N + gcol] = f2bf(v);
      }
    }
  }
}

// ------------- attention per (window, head): QK^T + bias, top-48 via radix-select, P@V -------------
__global__ __launch_bounds__(256) void attn_kern(const unsigned short* __restrict__ qkv,
                                                 const float* __restrict__ relb,
                                                 unsigned short* __restrict__ attnout) {
  __shared__ float Ss[64][66];
  __shared__ unsigned short VT[32][66];
  __shared__ float biasL[240];

  const int u = blockIdx.x;
  const int bwl = u >> 4, head = u & 15;
  const int tid = threadIdx.x;
  const int l = tid & 63, wv = tid >> 6;

  {
    const int row = tid >> 2, d0 = (tid & 3) * 8;
    short8 v8 = *(const short8*)(qkv + (size_t)(bwl * 64 + row) * 1536 + 1024 + head * 32 + d0);
#pragma unroll
    for (int j = 0; j < 8; ++j) VT[d0 + j][row] = (unsigned short)v8[j];
  }
  if (tid < 225) biasL[tid] = relb[tid * 16 + head];
  __syncthreads();

  {
    short8 a = *(const short8*)(qkv + (size_t)(bwl * 64 + wv * 16 + (l & 15)) * 1536 +
                                head * 32 + (l >> 4) * 8);
    const int n0 = wv * 16 + (l >> 4) * 4;
    const int m0 = l & 15;
    const int ibase = ((n0 >> 3) - (m0 >> 3) + 7) * 15 + ((n0 & 7) - (m0 & 7) + 7);
#pragma unroll
    for (int nt = 0; nt < 4; ++nt) {
      short8 bfr = *(const short8*)(qkv + (size_t)(bwl * 64 + nt * 16 + (l & 15)) * 1536 + 512 +
                                    head * 32 + (l >> 4) * 8);
      floatx4 z = {0.0f, 0.0f, 0.0f, 0.0f};
      floatx4 d = __builtin_amdgcn_mfma_f32_16x16x32_bf16(a, bfr, z, 0, 0, 0);
#pragma unroll
      for (int r = 0; r < 4; ++r)
        Ss[n0 + r][m0 + nt * 16] = fmaf(d[r], 0.17677669529663689f, biasL[ibase + r - 30 * nt]);
    }
  }

  float* srow_base = &Ss[wv * 16][0];
#pragma unroll 1
  for (int rr = 0; rr < 16; ++rr) {
    const float own = srow_base[rr * 66 + l];
    const unsigned int uo = __float_as_uint(own);
    const unsigned int mapped = uo ^ ((unsigned int)((int)uo >> 31) | 0x80000000u);
    unsigned int p = 0;
#pragma unroll 1
    for (int b = 31; b >= 0; --b) {
      const unsigned int cand = p | (1u << b);
      const int c = __popcll(__ballot(mapped >= cand));
      if (c >= 48) {
        p = cand;
        if (c == 48) break;
      }
    }
    const float tf = __uint_as_float((p & 0x80000000u) ? (p ^ 0x80000000u) : ~p);
    const float e = (mapped >= p) ? __expf(own - tf) : 0.0f;
    float zs = grpsum16(e);
    zs += swz16(zs);
    zs += __shfl_xor(zs, 32, 64);
    ((unsigned short*)(srow_base + rr * 66))[l] = f2bf(e * __builtin_amdgcn_rcpf(zs));
  }

  {
    floatx4 acc[2];
    acc[0] = {0.0f, 0.0f, 0.0f, 0.0f};
    acc[1] = {0.0f, 0.0f, 0.0f, 0.0f};
#pragma unroll
    for (int kh = 0; kh < 2; ++kh) {
      short8 pa = *(const short8*)((const unsigned short*)&Ss[wv * 16 + (l & 15)][0] +
                                   kh * 32 + (l >> 4) * 8);
#pragma unroll
      for (int nt = 0; nt < 2; ++nt) {
        short8 vb = *(const short8*)&VT[nt * 16 + (l & 15)][kh * 32 + (l >> 4) * 8];
        acc[nt] = __builtin_amdgcn_mfma_f32_16x16x32_bf16(pa, vb, acc[nt], 0, 0, 0);
      }
    }
#pragma unroll
    for (int nt = 0; nt < 2; ++nt)
#pragma unroll
      for (int r = 0; r < 4; ++r) {
        const int n = wv * 16 + (l >> 4) * 4 + r;
        const int dcol = nt * 16 + (l & 15);
        attnout[(size_t)(bwl * 64 + n) * 512 + head * 32 + dcol] = f2bf(acc[nt][r]);
      }
  }
}

// ---------------- launcher ----------------
extern "C" void kernel_launch(void* const* d_in, const int* in_sizes, int n_in,
                              void* d_out, int out_size, void* d_ws, size_t ws_size,
                              hipStream_t stream) {
  (void)in_sizes; (void)n_in; (void)out_size;
  const float* x      = (const float*)d_in[0];
  const float* n1g    = (const float*)d_in[1];
  const float* n1b    = (const float*)d_in[2];
  const float* qkv_w  = (const float*)d_in[3];
  const float* qkv_b  = (const float*)d_in[4];
  const float* relb   = (const float*)d_in[5];
  const float* proj_w = (const float*)d_in[6];
  const float* proj_b = (const float*)d_in[7];
  const float* n2g    = (const float*)d_in[8];
  const float* n2b    = (const float*)d_in[9];
  const float* fc1_w  = (const float*)d_in[10];
  const float* fc1_b  = (const float*)d_in[11];
  const float* fc2_w  = (const float*)d_in[12];
  const float* fc2_b  = (const float*)d_in[13];
  float* outp = (float*)d_out;               // final output only (EPI3)

  // ws layout: [weightsT 6.3MiB][x2bf 64MiB][bufA][bufB]
  unsigned short* qkvT  = (unsigned short*)d_ws;
  unsigned short* projT = qkvT + 1536 * 512;
  unsigned short* fc1T  = projT + 512 * 512;
  unsigned short* fc2T  = fc1T + 2048 * 512;
  const size_t wbytes = (size_t)(1536 * 512 + 512 * 512 + 2048 * 512 + 512 * 2048) * 2;
  unsigned short* x2bf = (unsigned short*)((char*)d_ws + wbytes);   // 65536x512 bf16 = 64MiB
  const size_t x2bytes = (size_t)65536 * 512 * 2;
  size_t rem = (ws_size > wbytes + x2bytes) ? ws_size - wbytes - x2bytes : 0;
  int R = (int)(rem / 5120);
  R = (R / 4096) * 4096;
  if (R > 16384) R = 16384;
  if (R < 4096) R = 4096;
  const int nch = 65536 / R;
  unsigned short* bufA = x2bf + (size_t)65536 * 512;
  unsigned short* bufB = bufA + (size_t)R * 512;

  transpose_kern<<<dim3(1536 / 32, 512 / 32), 256, 0, stream>>>(qkv_w, qkvT, 512, 1536);
  transpose_kern<<<dim3(512 / 32, 512 / 32), 256, 0, stream>>>(proj_w, projT, 512, 512);
  transpose_kern<<<dim3(2048 / 32, 512 / 32), 256, 0, stream>>>(fc1_w, fc1T, 512, 2048);
  transpose_kern<<<dim3(512 / 32, 2048 / 32), 256, 0, stream>>>(fc2_w, fc2T, 2048, 512);

  // merged per-chunk pipeline; x2 state kept bf16 in ws
  for (int cb = 0; cb < nch; ++cb) {
    ln_kern<0><<<R, 256, 0, stream>>>(x, n1g, n1b, bufA, cb * R, 1);
    gemm_bt<0><<<dim3(12, R / 128), 256, 0, stream>>>(bufA, qkvT, qkv_b, bufB, nullptr,
                                                      R, 1536, 512, 0);
    attn_kern<<<(R / 64) * 16, 256, 0, stream>>>(bufB, relb, bufA);
    gemm_bt<2><<<dim3(4, R / 128), 256, 0, stream>>>(bufA, projT, proj_b, x2bf, x,
                                                     R, 512, 512, cb * R);
    ln_kern<1><<<R, 256, 0, stream>>>(x2bf, n2g, n2b, bufA, cb * R, 0);
    gemm256<1><<<dim3(2048 / 256, R / 256), 512, 0, stream>>>(bufA, fc1T, fc1_b, bufB,
                                                              R, 2048, 512);
    gemm_bt<3><<<dim3(4, R / 128), 256, 0, stream>>>(bufB, fc2T, fc2_b,
                                                     outp + (size_t)cb * R * 512,
                                                     x2bf + (size_t)cb * R * 512,
                                                     R, 512, 2048, 0);
  }
}